// Round 14
// baseline (158.076 us; speedup 1.0000x reference)
//
#include <hip/hip_runtime.h>

// Problem constants (from reference)
static constexpr int kB = 2, kS = 2048, kD = 1024, kFF = 4096;
static constexpr int kM = kB * kS;  // 4096 token rows
static constexpr size_t MB = 1u << 20;

typedef __attribute__((ext_vector_type(8))) short short8;
typedef __attribute__((ext_vector_type(8))) unsigned short ushort8;
typedef __attribute__((ext_vector_type(4))) float f32x4;

__device__ __forceinline__ unsigned short f2bf(float f) {
  union { float f; unsigned int u; } c; c.f = f;
  unsigned int u = c.u;
  unsigned int r = u + 0x7FFFu + ((u >> 16) & 1u);  // RNE
  return (unsigned short)(r >> 16);
}

__device__ __forceinline__ float bf2f(unsigned short b) {
  union { unsigned int u; float f; } c;
  c.u = ((unsigned int)b) << 16;
  return c.f;
}

__device__ __forceinline__ void gload_lds16(const void* g, void* l) {
  __builtin_amdgcn_global_load_lds(
      (const __attribute__((address_space(1))) void*)g,
      (__attribute__((address_space(3))) void*)l, 16, 0, 0);
}

// ------ cast+transpose 64x64 tile helper (used inside merged prep kernel) ------
__device__ __forceinline__ void do_ct64(
    const float* __restrict__ W, unsigned short* __restrict__ Wt,
    int K, int N, float scale, int ntN, int b, float (*tile)[65]) {
  const int nb = (b % ntN) * 64, kb = (b / ntN) * 64;
  const int tx = threadIdx.x & 15, ty = threadIdx.x >> 4;
#pragma unroll
  for (int p = 0; p < 4; ++p) {
    const int r = ty + 16 * p;
    float4 v = *(const float4*)(W + (size_t)(kb + r) * N + nb + tx * 4);
    tile[r][tx * 4 + 0] = v.x;
    tile[r][tx * 4 + 1] = v.y;
    tile[r][tx * 4 + 2] = v.z;
    tile[r][tx * 4 + 3] = v.w;
  }
  __syncthreads();
#pragma unroll
  for (int p = 0; p < 4; ++p) {
    const int n = ty + 16 * p;
    ushort4 o;
    o.x = f2bf(tile[tx * 4 + 0][n] * scale);
    o.y = f2bf(tile[tx * 4 + 1][n] * scale);
    o.z = f2bf(tile[tx * 4 + 2][n] * scale);
    o.w = f2bf(tile[tx * 4 + 3][n] * scale);
    *(ushort4*)(Wt + (size_t)(nb + n) * K + kb + tx * 4) = o;
  }
}

// ---- merged weight prep: Wo^T(x2048), W1^T, W2^T, cast(Wv), bias-GEMV part ----
__global__ __launch_bounds__(256) void prep_kernel(
    const float* __restrict__ Wo, const float* __restrict__ Wv,
    const float* __restrict__ W1, const float* __restrict__ W2,
    const float* __restrict__ bv,
    unsigned short* __restrict__ WoT, unsigned short* __restrict__ WvBf,
    unsigned short* __restrict__ W1T, unsigned short* __restrict__ W2T,
    float* __restrict__ bprt) {
  __shared__ float tile[64][65];
  const int b = blockIdx.x;
  if (b < 256) {
    do_ct64(Wo, WoT, kD, kD, (float)kS, 16, b, tile);
  } else if (b < 1280) {
    do_ct64(W1, W1T, kD, kFF, 1.0f, 64, b - 256, tile);
  } else if (b < 2304) {
    do_ct64(W2, W2T, kFF, kD, 1.0f, 16, b - 1280, tile);
  } else if (b < 3328) {
    const int i = ((b - 2304) * 256 + threadIdx.x) * 4;
    float4 v = *(const float4*)(Wv + i);
    ushort4 o;
    o.x = f2bf(v.x); o.y = f2bf(v.y); o.z = f2bf(v.z); o.w = f2bf(v.w);
    *(ushort4*)(WvBf + i) = o;
  } else {
    const int bb = b - 3328, t = threadIdx.x;
    const int c = t * 4;
    float4 acc = {0.f, 0.f, 0.f, 0.f};
#pragma unroll
    for (int r = 0; r < 8; ++r) {
      const int f = bb * 8 + r;
      const float s = bv[f];
      float4 w = *(const float4*)(Wo + (size_t)f * 1024 + c);
      acc.x = fmaf(s, w.x, acc.x);
      acc.y = fmaf(s, w.y, acc.y);
      acc.z = fmaf(s, w.z, acc.z);
      acc.w = fmaf(s, w.w, acc.w);
    }
    *(float4*)(bprt + (size_t)bb * 1024 + c) = acc;
  }
}

// -------- combine 4 bf16 Wc partials + I -> WcT bf16; blocks 0-3 also finish bc ----
__global__ __launch_bounds__(256) void combine_wc4_fin_kernel(
    const unsigned short* __restrict__ P, unsigned short* __restrict__ Wt,
    const float* __restrict__ bprt, const float* __restrict__ bo,
    float* __restrict__ bc) {
  const int i = (blockIdx.x * 256 + threadIdx.x) * 4;  // grid 1024
  const int MN = 1024 * 1024;
  ushort4 s0 = *(const ushort4*)(P + i);
  ushort4 s1 = *(const ushort4*)(P + MN + i);
  ushort4 s2 = *(const ushort4*)(P + 2 * MN + i);
  ushort4 s3 = *(const ushort4*)(P + 3 * MN + i);
  const int row = i >> 10, col = i & 1023;
  float v0 = bf2f(s0.x) + bf2f(s1.x) + bf2f(s2.x) + bf2f(s3.x) + (row == col + 0 ? 1.0f : 0.0f);
  float v1 = bf2f(s0.y) + bf2f(s1.y) + bf2f(s2.y) + bf2f(s3.y) + (row == col + 1 ? 1.0f : 0.0f);
  float v2 = bf2f(s0.z) + bf2f(s1.z) + bf2f(s2.z) + bf2f(s3.z) + (row == col + 2 ? 1.0f : 0.0f);
  float v3 = bf2f(s0.w) + bf2f(s1.w) + bf2f(s2.w) + bf2f(s3.w) + (row == col + 3 ? 1.0f : 0.0f);
  ushort4 o; o.x = f2bf(v0); o.y = f2bf(v1); o.z = f2bf(v2); o.w = f2bf(v3);
  *(ushort4*)(Wt + i) = o;
  if (blockIdx.x < 4) {
    const int n = blockIdx.x * 256 + threadIdx.x;
    float acc = 0.0f;
#pragma unroll 8
    for (int bb = 0; bb < 128; ++bb) acc += bprt[(size_t)bb * 1024 + n];
    bc[n] = 2048.0f * acc + bo[n];
  }
}

// ---------------- 128x128 GEMM (kept for the small Wc product) ----------------
template <int OUT_BF16, int RELU, int A_F32>
__global__ __launch_bounds__(256, 4) void gemm_bt(
    const void* __restrict__ A, const unsigned short* __restrict__ Bt,
    const float* __restrict__ bias, void* __restrict__ Cout,
    int M, int N, int K, int nXtiles, int nTilesPerSplit, int kSplitLen,
    size_t cStride, int cr, int cc) {
  __shared__ __align__(16) unsigned short sA[128 * 64];
  __shared__ __align__(16) unsigned short sB[128 * 64];
  const unsigned short* Ab = (const unsigned short*)A;
  const int tid = threadIdx.x;
  const int wave = tid >> 6, lane = tid & 63;
  const int wr = wave >> 1, wc = wave & 1;

  const int x = blockIdx.x & 7, j = blockIdx.x >> 3;
  const int bpc = cr * cc;
  const int chunkIdx = x + 8 * (j / bpc);
  const int w = j % bpc;
  const int chunksPerSplit = nTilesPerSplit / bpc;
  const int split = chunkIdx / chunksPerSplit;
  const int cL = chunkIdx % chunksPerSplit;
  const int cpr = nXtiles / cc;
  const int m0 = ((cL / cpr) * cr + w / cc) * 128;
  const int n0 = ((cL % cpr) * cc + w % cc) * 128;
  const int kBeg = split * kSplitLen, kEnd = kBeg + kSplitLen;

  const int srow = lane >> 3;
  const int scol = ((lane & 7) ^ srow) * 8;

  f32x4 acc[4][4] = {};

  for (int k0 = kBeg; k0 < kEnd; k0 += 64) {
#pragma unroll
    for (int i = 0; i < 4; ++i) {
      const int chunk = i * 4 + wave;
      const int rr = chunk * 8 + srow;
      gload_lds16(Ab + (size_t)(m0 + rr) * K + (k0 + scol), &sA[chunk * 512]);
      gload_lds16(Bt + (size_t)(n0 + rr) * K + (k0 + scol), &sB[chunk * 512]);
    }
    __syncthreads();
#pragma unroll
    for (int kk = 0; kk < 64; kk += 32) {
      const int kcol = kk + (lane >> 4) * 8;
      const int kswz = (lane & 7) * 8;
      short8 af[4], bfr[4];
#pragma unroll
      for (int m = 0; m < 4; ++m)
        af[m] = *(const short8*)&sA[(wr * 64 + m * 16 + (lane & 15)) * 64 + (kcol ^ kswz)];
#pragma unroll
      for (int n = 0; n < 4; ++n)
        bfr[n] = *(const short8*)&sB[(wc * 64 + n * 16 + (lane & 15)) * 64 + (kcol ^ kswz)];
#pragma unroll
      for (int m = 0; m < 4; ++m)
#pragma unroll
        for (int n = 0; n < 4; ++n)
          acc[m][n] = __builtin_amdgcn_mfma_f32_16x16x32_bf16(af[m], bfr[n], acc[m][n], 0, 0, 0);
    }
    __syncthreads();
  }

  const int cl = lane & 15, rg = lane >> 4;
  const float* bptr = (split == 0) ? bias : nullptr;
#pragma unroll
  for (int n = 0; n < 4; ++n) {
    const int col = n0 + wc * 64 + n * 16 + cl;
    const float bias_v = bptr ? bptr[col] : 0.0f;
#pragma unroll
    for (int m = 0; m < 4; ++m) {
      const int rbase = m0 + wr * 64 + m * 16 + rg * 4;
#pragma unroll
      for (int j2 = 0; j2 < 4; ++j2) {
        float v = acc[m][n][j2] + bias_v;
        if (RELU) v = fmaxf(v, 0.0f);
        const size_t idx = split * cStride + (size_t)(rbase + j2) * N + col;
        if (OUT_BF16)
          ((unsigned short*)Cout)[idx] = f2bf(v);
        else
          ((float*)Cout)[idx] = v;
      }
    }
  }
}

// ========== 256x128 GEMM: wave-tile 128x64 to halve LDS-bytes/MFMA ==========
// 4 waves (2M x 2N), BK=64, LDS 48KB, 2 blocks/CU (reg-capped: acc 8x4 f32x4).
// LDS:MFMA cycle ratio drops 3.2 -> ~1.2 (the 128^2 kernel measured EXACTLY at
// its 31% LDS-BW ceiling; this tile's ceiling is ~85%). Same 2-barrier m97
// schedule, same XOR swizzle (128B rows, 8 slots -> conflict-free), same XCD
// super-chunk mapping. A_F32: stage A fp32->reg->cvt->ds_write (z-cast fusion).
template <int OUT_BF16, int RELU, int A_F32>
__global__ __launch_bounds__(256, 2) void gemm_wide(
    const void* __restrict__ A, const unsigned short* __restrict__ Bt,
    const float* __restrict__ bias, void* __restrict__ Cout,
    int M, int N, int K, int nXtiles, int nTilesPerSplit, int kSplitLen,
    size_t cStride, int cr, int cc) {
  __shared__ __align__(16) unsigned short sA[256 * 64];  // 32KB
  __shared__ __align__(16) unsigned short sB[128 * 64];  // 16KB
  const unsigned short* Ab = (const unsigned short*)A;
  const float* Af = (const float*)A;
  const int tid = threadIdx.x;
  const int wave = tid >> 6, lane = tid & 63;
  const int wr = wave >> 1, wc = wave & 1;
  const int l15 = lane & 15, l7 = lane & 7, l4 = lane >> 4;

  // super-chunk XCD decomposition (tile units: 256-row x 128-col)
  const int x = blockIdx.x & 7, j = blockIdx.x >> 3;
  const int bpc = cr * cc;
  const int chunkIdx = x + 8 * (j / bpc);
  const int w = j % bpc;
  const int chunksPerSplit = nTilesPerSplit / bpc;
  const int split = chunkIdx / chunksPerSplit;
  const int cL = chunkIdx % chunksPerSplit;
  const int cpr = nXtiles / cc;
  const int m0 = ((cL / cpr) * cr + w / cc) * 256;
  const int n0 = ((cL % cpr) * cc + w % cc) * 128;
  const int kBeg = split * kSplitLen, kEnd = kBeg + kSplitLen;

  const int srow = lane >> 3;
  const int scol = (l7 ^ srow) * 8;  // pre-swizzled source col (elements)

  f32x4 acc[8][4] = {};

  for (int k0 = kBeg; k0 < kEnd; k0 += 64) {
    // B: 16 chunks of 8 rows (4/wave), async gload_lds
#pragma unroll
    for (int i = 0; i < 4; ++i) {
      const int chunk = i * 4 + wave;
      const int rr = chunk * 8 + srow;
      gload_lds16(Bt + (size_t)(n0 + rr) * K + (k0 + scol), &sB[chunk * 512]);
    }
    // A: 32 chunks of 8 rows (8/wave)
    if constexpr (A_F32) {
#pragma unroll
      for (int h = 0; h < 2; ++h) {
        float4 pa[4][2];
#pragma unroll
        for (int i = 0; i < 4; ++i) {
          const int chunk = (h * 4 + i) * 4 + wave;
          const int rr = chunk * 8 + srow;
          const float* az = Af + (size_t)(m0 + rr) * K + (k0 + scol);
          pa[i][0] = *(const float4*)az;
          pa[i][1] = *(const float4*)(az + 4);
        }
#pragma unroll
        for (int i = 0; i < 4; ++i) {
          const int chunk = (h * 4 + i) * 4 + wave;
          short8 cv;
          cv[0] = (short)f2bf(pa[i][0].x); cv[1] = (short)f2bf(pa[i][0].y);
          cv[2] = (short)f2bf(pa[i][0].z); cv[3] = (short)f2bf(pa[i][0].w);
          cv[4] = (short)f2bf(pa[i][1].x); cv[5] = (short)f2bf(pa[i][1].y);
          cv[6] = (short)f2bf(pa[i][1].z); cv[7] = (short)f2bf(pa[i][1].w);
          *(short8*)&sA[chunk * 512 + lane * 8] = cv;
        }
      }
    } else {
#pragma unroll
      for (int i = 0; i < 8; ++i) {
        const int chunk = i * 4 + wave;
        const int rr = chunk * 8 + srow;
        gload_lds16(Ab + (size_t)(m0 + rr) * K + (k0 + scol), &sA[chunk * 512]);
      }
    }
    __syncthreads();
#pragma unroll
    for (int kk = 0; kk < 64; kk += 32) {
      const int kcol = kk + l4 * 8;
      const int kswz = l7 * 8;
      const int kr = kcol ^ kswz;
      short8 af[8], bfr[4];
#pragma unroll
      for (int m = 0; m < 8; ++m)
        af[m] = *(const short8*)&sA[(wr * 128 + m * 16 + l15) * 64 + kr];
#pragma unroll
      for (int n = 0; n < 4; ++n)
        bfr[n] = *(const short8*)&sB[(wc * 64 + n * 16 + l15) * 64 + kr];
#pragma unroll
      for (int m = 0; m < 8; ++m)
#pragma unroll
        for (int n = 0; n < 4; ++n)
          acc[m][n] = __builtin_amdgcn_mfma_f32_16x16x32_bf16(af[m], bfr[n], acc[m][n], 0, 0, 0);
    }
    __syncthreads();
  }

  const float* bptr = (split == 0) ? bias : nullptr;
#pragma unroll
  for (int n = 0; n < 4; ++n) {
    const int col = n0 + wc * 64 + n * 16 + l15;
    const float bias_v = bptr ? bptr[col] : 0.0f;
#pragma unroll
    for (int m = 0; m < 8; ++m) {
      const int rbase = m0 + wr * 128 + m * 16 + l4 * 4;
#pragma unroll
      for (int j2 = 0; j2 < 4; ++j2) {
        float v = acc[m][n][j2] + bias_v;
        if (RELU) v = fmaxf(v, 0.0f);
        const size_t idx = split * cStride + (size_t)(rbase + j2) * N + col;
        if (OUT_BF16)
          ((unsigned short*)Cout)[idx] = f2bf(v);
        else
          ((float*)Cout)[idx] = v;
      }
    }
  }
}

// -------- LN (wave-per-row): h1 = LN(sum of 4 bf16 partials) -> bf16 --------
__global__ __launch_bounds__(256) void ln4_wave_kernel(
    const unsigned short* __restrict__ P, size_t pStr,
    const float* __restrict__ gg, const float* __restrict__ bb,
    unsigned short* __restrict__ Hb) {
  const int wave = threadIdx.x >> 6, lane = threadIdx.x & 63;
  const int row = blockIdx.x * 4 + wave;
  const size_t rbase = (size_t)row * 1024;
  float a[16];
#pragma unroll
  for (int sw = 0; sw < 2; ++sw) {
    const size_t idx = rbase + sw * 512 + lane * 8;
    ushort8 v0 = *(const ushort8*)(P + idx);
    ushort8 v1 = *(const ushort8*)(P + pStr + idx);
    ushort8 v2 = *(const ushort8*)(P + 2 * pStr + idx);
    ushort8 v3 = *(const ushort8*)(P + 3 * pStr + idx);
#pragma unroll
    for (int j = 0; j < 8; ++j)
      a[sw * 8 + j] = bf2f(v0[j]) + bf2f(v1[j]) + bf2f(v2[j]) + bf2f(v3[j]);
  }
  float s = 0.f, ss = 0.f;
#pragma unroll
  for (int j = 0; j < 16; ++j) { s += a[j]; ss += a[j] * a[j]; }
#pragma unroll
  for (int off = 32; off > 0; off >>= 1) {
    s += __shfl_down(s, off);
    ss += __shfl_down(ss, off);
  }
  s = __shfl(s, 0);
  ss = __shfl(ss, 0);
  const float mean = s * (1.0f / 1024.0f);
  const float rstd = rsqrtf(ss * (1.0f / 1024.0f) - mean * mean + 1e-5f);
#pragma unroll
  for (int sw = 0; sw < 2; ++sw) {
    const int cbase = sw * 512 + lane * 8;
    float4 g0 = *(const float4*)(gg + cbase);
    float4 g1 = *(const float4*)(gg + cbase + 4);
    float4 b0 = *(const float4*)(bb + cbase);
    float4 b1 = *(const float4*)(bb + cbase + 4);
    const float* gp0 = &g0.x; const float* gp1 = &g1.x;
    const float* bp0 = &b0.x; const float* bp1 = &b1.x;
    ushort8 o;
#pragma unroll
    for (int j = 0; j < 4; ++j) {
      o[j]     = f2bf((a[sw * 8 + j]     - mean) * rstd * gp0[j] + bp0[j]);
      o[4 + j] = f2bf((a[sw * 8 + 4 + j] - mean) * rstd * gp1[j] + bp1[j]);
    }
    *(ushort8*)(Hb + rbase + cbase) = o;
  }
}

// -------- LN (wave-per-row): out = LN(h1 + sum of 4 bf16 partials) -> fp32 --------
__global__ __launch_bounds__(256) void ln_fin_wave_kernel(
    const unsigned short* __restrict__ Res, const unsigned short* __restrict__ P,
    size_t pStr, const float* __restrict__ gg, const float* __restrict__ bb,
    float* __restrict__ out) {
  const int wave = threadIdx.x >> 6, lane = threadIdx.x & 63;
  const int row = blockIdx.x * 4 + wave;
  const size_t rbase = (size_t)row * 1024;
  float a[16];
#pragma unroll
  for (int sw = 0; sw < 2; ++sw) {
    const size_t idx = rbase + sw * 512 + lane * 8;
    ushort8 rv = *(const ushort8*)(Res + idx);
    ushort8 v0 = *(const ushort8*)(P + idx);
    ushort8 v1 = *(const ushort8*)(P + pStr + idx);
    ushort8 v2 = *(const ushort8*)(P + 2 * pStr + idx);
    ushort8 v3 = *(const ushort8*)(P + 3 * pStr + idx);
#pragma unroll
    for (int j = 0; j < 8; ++j)
      a[sw * 8 + j] = bf2f(rv[j]) + bf2f(v0[j]) + bf2f(v1[j]) + bf2f(v2[j]) + bf2f(v3[j]);
  }
  float s = 0.f, ss = 0.f;
#pragma unroll
  for (int j = 0; j < 16; ++j) { s += a[j]; ss += a[j] * a[j]; }
#pragma unroll
  for (int off = 32; off > 0; off >>= 1) {
    s += __shfl_down(s, off);
    ss += __shfl_down(ss, off);
  }
  s = __shfl(s, 0);
  ss = __shfl(ss, 0);
  const float mean = s * (1.0f / 1024.0f);
  const float rstd = rsqrtf(ss * (1.0f / 1024.0f) - mean * mean + 1e-5f);
#pragma unroll
  for (int sw = 0; sw < 2; ++sw) {
    const int cbase = sw * 512 + lane * 8;
    float4 g0 = *(const float4*)(gg + cbase);
    float4 g1 = *(const float4*)(gg + cbase + 4);
    float4 b0 = *(const float4*)(bb + cbase);
    float4 b1 = *(const float4*)(bb + cbase + 4);
    const float* gp0 = &g0.x; const float* gp1 = &g1.x;
    const float* bp0 = &b0.x; const float* bp1 = &b1.x;
    float4 o0, o1;
    float* op0 = &o0.x; float* op1 = &o1.x;
#pragma unroll
    for (int j = 0; j < 4; ++j) {
      op0[j] = (a[sw * 8 + j]     - mean) * rstd * gp0[j] + bp0[j];
      op1[j] = (a[sw * 8 + 4 + j] - mean) * rstd * gp1[j] + bp1[j];
    }
    *(float4*)(out + rbase + cbase) = o0;
    *(float4*)(out + rbase + cbase + 4) = o1;
  }
}

// ---------------------------------------------------------------------------
// Attention is algebraically dead: softmax over q sums to 1 per (b,h,k) column;
// summed over k -> s_bh == S == 2048 exactly. Folding the residual too:
//   h1  = LN( z @ (I + 2048*Wv@Wo) + (2048*bv@Wo + bo) )
//   out = LN( h1 + relu(h1@W1+b1)@W2 + b2 )
// q, k, mask, x, y, Wq, Wk are all unused.
// ---------------------------------------------------------------------------
extern "C" void kernel_launch(void* const* d_in, const int* in_sizes, int n_in,
                              void* d_out, int out_size, void* d_ws, size_t ws_size,
                              hipStream_t stream) {
  const float* z  = (const float*)d_in[2];
  const float* Wv = (const float*)d_in[8];
  const float* bv = (const float*)d_in[9];
  const float* Wo = (const float*)d_in[10];
  const float* bo = (const float*)d_in[11];
  const float* W1 = (const float*)d_in[12];
  const float* b1 = (const float*)d_in[13];
  const float* W2 = (const float*)d_in[14];
  const float* b2 = (const float*)d_in[15];
  const float* lng = (const float*)d_in[16];
  const float* lnb = (const float*)d_in[17];
  float* out = (float*)d_out;

  char* ws = (char*)d_ws;
  unsigned short* a1   = (unsigned short*)(ws + 0 * MB);
  unsigned short* attP = (unsigned short*)(ws + 32 * MB);
  unsigned short* ffP  = (unsigned short*)(ws + 32 * MB);
  unsigned short* W2T  = (unsigned short*)(ws + 64 * MB);
  unsigned short* wcpB = (unsigned short*)(ws + 72 * MB);
  unsigned short* WoT  = (unsigned short*)(ws + 88 * MB);
  unsigned short* WvBf = (unsigned short*)(ws + 90 * MB);
  unsigned short* WcT  = (unsigned short*)(ws + 92 * MB);
  float*          bc   = (float*)(ws + 94 * MB);
  float*          bprt = (float*)(ws + 94 * MB + 65536);
  unsigned short* h1bf = (unsigned short*)(ws + 96 * MB);
  unsigned short* W1T  = (unsigned short*)(ws + 104 * MB);

  const size_t pStr = (size_t)kM * kD;     // elements per activation partial
  const size_t wStr = (size_t)kD * kD;     // elements per Wc partial

  // 1) merged weight prep (WoT, W1T, W2T, WvBf, bprt)
  prep_kernel<<<dim3(3456), dim3(256), 0, stream>>>(
      Wo, Wv, W1, W2, bv, WoT, WvBf, W1T, W2T, bprt);

  // 2) Wc partials = (2048*Wv@Wo)^T : 128^2 kernel, split-K x4 (grid 256)
  gemm_bt<1, 0, 0><<<dim3(256), dim3(256), 0, stream>>>(
      WoT, WvBf, nullptr, wcpB, kD, kD, kD, kD / 128, 64, 256, wStr, 8, 4);

  // 3) WcT = sum of partials + I (bf16); blocks 0-3 also finish bc
  combine_wc4_fin_kernel<<<dim3(1024), dim3(256), 0, stream>>>(
      wcpB, WcT, bprt, bo, bc);

  // 4) attP = z @ WcT^T + bc : wide tile, split-K x4 (grid 512, K=4 steps),
  //    A staged fp32->bf16 in-kernel. tiles 16Mx8N, chunk 4x8.
  gemm_wide<1, 0, 1><<<dim3(512), dim3(256), 0, stream>>>(
      z, WcT, bc, attP, kM, kD, kD, kD / 128, 128, 256, pStr, 4, 8);

  // 5) h1 = LN(attP0..3) -> bf16 (wave-per-row)
  ln4_wave_kernel<<<dim3(kM / 4), dim3(256), 0, stream>>>(
      attP, pStr, lng, lnb, h1bf);

  // 6) FF1: a1 = relu(h1 @ W1 + b1) : wide tile, grid 512 (16Mx32N), chunk 4x16
  gemm_wide<1, 1, 0><<<dim3(512), dim3(256), 0, stream>>>(
      h1bf, W1T, b1, a1, kM, kFF, kD, kFF / 128, 512, kD, 0, 4, 16);

  // 7) FF2: ffP = a1 @ W2 + b2 : wide tile, split-K x4 (grid 512, K=16 steps)
  gemm_wide<1, 0, 0><<<dim3(512), dim3(256), 0, stream>>>(
      a1, W2T, b2, ffP, kM, kD, kFF, kD / 128, 128, kFF / 4, pStr, 4, 8);

  // 8) out = LN(h1 + ffP0..3) (wave-per-row)
  ln_fin_wave_kernel<<<dim3(kM / 4), dim3(256), 0, stream>>>(
      h1bf, ffP, pStr, lng, lnb, out);
}

// Round 15
// 157.709 us; speedup vs baseline: 1.0023x; 1.0023x over previous
//
#include <hip/hip_runtime.h>

// Problem constants (from reference)
static constexpr int kB = 2, kS = 2048, kD = 1024, kFF = 4096;
static constexpr int kM = kB * kS;  // 4096 token rows
static constexpr size_t MB = 1u << 20;

typedef __attribute__((ext_vector_type(8))) short short8;
typedef __attribute__((ext_vector_type(8))) unsigned short ushort8;
typedef __attribute__((ext_vector_type(4))) float f32x4;

__device__ __forceinline__ unsigned short f2bf(float f) {
  union { float f; unsigned int u; } c; c.f = f;
  unsigned int u = c.u;
  unsigned int r = u + 0x7FFFu + ((u >> 16) & 1u);  // RNE
  return (unsigned short)(r >> 16);
}

__device__ __forceinline__ float bf2f(unsigned short b) {
  union { unsigned int u; float f; } c;
  c.u = ((unsigned int)b) << 16;
  return c.f;
}

__device__ __forceinline__ void gload_lds16(const void* g, void* l) {
  __builtin_amdgcn_global_load_lds(
      (const __attribute__((address_space(1))) void*)g,
      (__attribute__((address_space(3))) void*)l, 16, 0, 0);
}

// ------ cast+transpose 64x64 tile helper (used inside merged prep kernel) ------
__device__ __forceinline__ void do_ct64(
    const float* __restrict__ W, unsigned short* __restrict__ Wt,
    int K, int N, float scale, int ntN, int b, float (*tile)[65]) {
  const int nb = (b % ntN) * 64, kb = (b / ntN) * 64;
  const int tx = threadIdx.x & 15, ty = threadIdx.x >> 4;
#pragma unroll
  for (int p = 0; p < 4; ++p) {
    const int r = ty + 16 * p;
    float4 v = *(const float4*)(W + (size_t)(kb + r) * N + nb + tx * 4);
    tile[r][tx * 4 + 0] = v.x;
    tile[r][tx * 4 + 1] = v.y;
    tile[r][tx * 4 + 2] = v.z;
    tile[r][tx * 4 + 3] = v.w;
  }
  __syncthreads();
#pragma unroll
  for (int p = 0; p < 4; ++p) {
    const int n = ty + 16 * p;
    ushort4 o;
    o.x = f2bf(tile[tx * 4 + 0][n] * scale);
    o.y = f2bf(tile[tx * 4 + 1][n] * scale);
    o.z = f2bf(tile[tx * 4 + 2][n] * scale);
    o.w = f2bf(tile[tx * 4 + 3][n] * scale);
    *(ushort4*)(Wt + (size_t)(nb + n) * K + kb + tx * 4) = o;
  }
}

// ---- merged weight prep: Wo^T(x2048), W1^T, W2^T, cast(Wv), bias-GEMV part ----
__global__ __launch_bounds__(256) void prep_kernel(
    const float* __restrict__ Wo, const float* __restrict__ Wv,
    const float* __restrict__ W1, const float* __restrict__ W2,
    const float* __restrict__ bv,
    unsigned short* __restrict__ WoT, unsigned short* __restrict__ WvBf,
    unsigned short* __restrict__ W1T, unsigned short* __restrict__ W2T,
    float* __restrict__ bprt) {
  __shared__ float tile[64][65];
  const int b = blockIdx.x;
  if (b < 256) {
    do_ct64(Wo, WoT, kD, kD, (float)kS, 16, b, tile);
  } else if (b < 1280) {
    do_ct64(W1, W1T, kD, kFF, 1.0f, 64, b - 256, tile);
  } else if (b < 2304) {
    do_ct64(W2, W2T, kFF, kD, 1.0f, 16, b - 1280, tile);
  } else if (b < 3328) {
    const int i = ((b - 2304) * 256 + threadIdx.x) * 4;
    float4 v = *(const float4*)(Wv + i);
    ushort4 o;
    o.x = f2bf(v.x); o.y = f2bf(v.y); o.z = f2bf(v.z); o.w = f2bf(v.w);
    *(ushort4*)(WvBf + i) = o;
  } else {
    const int bb = b - 3328, t = threadIdx.x;
    const int c = t * 4;
    float4 acc = {0.f, 0.f, 0.f, 0.f};
#pragma unroll
    for (int r = 0; r < 8; ++r) {
      const int f = bb * 8 + r;
      const float s = bv[f];
      float4 w = *(const float4*)(Wo + (size_t)f * 1024 + c);
      acc.x = fmaf(s, w.x, acc.x);
      acc.y = fmaf(s, w.y, acc.y);
      acc.z = fmaf(s, w.z, acc.z);
      acc.w = fmaf(s, w.w, acc.w);
    }
    *(float4*)(bprt + (size_t)bb * 1024 + c) = acc;
  }
}

// -------- combine 4 bf16 Wc partials + I -> WcT bf16; blocks 0-3 also finish bc ----
__global__ __launch_bounds__(256) void combine_wc4_fin_kernel(
    const unsigned short* __restrict__ P, unsigned short* __restrict__ Wt,
    const float* __restrict__ bprt, const float* __restrict__ bo,
    float* __restrict__ bc) {
  const int i = (blockIdx.x * 256 + threadIdx.x) * 4;  // grid 1024
  const int MN = 1024 * 1024;
  ushort4 s0 = *(const ushort4*)(P + i);
  ushort4 s1 = *(const ushort4*)(P + MN + i);
  ushort4 s2 = *(const ushort4*)(P + 2 * MN + i);
  ushort4 s3 = *(const ushort4*)(P + 3 * MN + i);
  const int row = i >> 10, col = i & 1023;
  float v0 = bf2f(s0.x) + bf2f(s1.x) + bf2f(s2.x) + bf2f(s3.x) + (row == col + 0 ? 1.0f : 0.0f);
  float v1 = bf2f(s0.y) + bf2f(s1.y) + bf2f(s2.y) + bf2f(s3.y) + (row == col + 1 ? 1.0f : 0.0f);
  float v2 = bf2f(s0.z) + bf2f(s1.z) + bf2f(s2.z) + bf2f(s3.z) + (row == col + 2 ? 1.0f : 0.0f);
  float v3 = bf2f(s0.w) + bf2f(s1.w) + bf2f(s2.w) + bf2f(s3.w) + (row == col + 3 ? 1.0f : 0.0f);
  ushort4 o; o.x = f2bf(v0); o.y = f2bf(v1); o.z = f2bf(v2); o.w = f2bf(v3);
  *(ushort4*)(Wt + i) = o;
  if (blockIdx.x < 4) {
    const int n = blockIdx.x * 256 + threadIdx.x;
    float acc = 0.0f;
#pragma unroll 8
    for (int bb = 0; bb < 128; ++bb) acc += bprt[(size_t)bb * 1024 + n];
    bc[n] = 2048.0f * acc + bo[n];
  }
}

// ---------------- GEMM: C[M,N] = A[M,K] @ Bt[N,K]^T (+bias, relu, split-K) ----
// 128x128 tile, BK=64, 4 waves (2x2). Single 32KB LDS buffer (m97 structure;
// 4 blocks/CU TLP -- the hard cap: 60 VGPR + 64 acc-AGPR ~ 124 regs/wave;
// r14 proved bigger wave-tiles lose more to occupancy than they gain in LDS BW).
// T2 XOR-swizzle (0 conflicts measured). XCD super-chunk mapping (r10).
// A_F32: stage A fp32->reg->cvt->ds_write (fuses the z cast).
// bf16 C-store: shfl-paired ushort2 (halves epilogue store count).
template <int OUT_BF16, int RELU, int A_F32>
__global__ __launch_bounds__(256, 4) void gemm_bt(
    const void* __restrict__ A, const unsigned short* __restrict__ Bt,
    const float* __restrict__ bias, void* __restrict__ Cout,
    int M, int N, int K, int nXtiles, int nTilesPerSplit, int kSplitLen,
    size_t cStride, int cr, int cc) {
  __shared__ __align__(16) unsigned short sA[128 * 64];
  __shared__ __align__(16) unsigned short sB[128 * 64];
  const unsigned short* Ab = (const unsigned short*)A;
  const float* Af = (const float*)A;
  const int tid = threadIdx.x;
  const int wave = tid >> 6, lane = tid & 63;
  const int wr = wave >> 1, wc = wave & 1;

  // super-chunk XCD decomposition (bijective; (nwg/8) % (cr*cc) == 0)
  const int x = blockIdx.x & 7, j = blockIdx.x >> 3;
  const int bpc = cr * cc;
  const int chunkIdx = x + 8 * (j / bpc);
  const int w = j % bpc;
  const int chunksPerSplit = nTilesPerSplit / bpc;
  const int split = chunkIdx / chunksPerSplit;
  const int cL = chunkIdx % chunksPerSplit;
  const int cpr = nXtiles / cc;
  const int m0 = ((cL / cpr) * cr + w / cc) * 128;
  const int n0 = ((cL % cpr) * cc + w % cc) * 128;
  const int kBeg = split * kSplitLen, kEnd = kBeg + kSplitLen;

  const int srow = lane >> 3;
  const int scol = ((lane & 7) ^ srow) * 8;  // pre-swizzled global col (elements)

  f32x4 acc[4][4] = {};

  for (int k0 = kBeg; k0 < kEnd; k0 += 64) {
    if constexpr (A_F32) {
      float4 pa[4][2];
#pragma unroll
      for (int i = 0; i < 4; ++i) {
        const int chunk = i * 4 + wave;
        const int rr = chunk * 8 + srow;
        const float* az = Af + (size_t)(m0 + rr) * K + (k0 + scol);
        pa[i][0] = *(const float4*)az;
        pa[i][1] = *(const float4*)(az + 4);
      }
#pragma unroll
      for (int i = 0; i < 4; ++i) {
        const int chunk = i * 4 + wave;
        short8 cv;
        cv[0] = (short)f2bf(pa[i][0].x); cv[1] = (short)f2bf(pa[i][0].y);
        cv[2] = (short)f2bf(pa[i][0].z); cv[3] = (short)f2bf(pa[i][0].w);
        cv[4] = (short)f2bf(pa[i][1].x); cv[5] = (short)f2bf(pa[i][1].y);
        cv[6] = (short)f2bf(pa[i][1].z); cv[7] = (short)f2bf(pa[i][1].w);
        *(short8*)&sA[chunk * 512 + lane * 8] = cv;
      }
    } else {
#pragma unroll
      for (int i = 0; i < 4; ++i) {
        const int chunk = i * 4 + wave;
        const int rr = chunk * 8 + srow;
        gload_lds16(Ab + (size_t)(m0 + rr) * K + (k0 + scol), &sA[chunk * 512]);
      }
    }
#pragma unroll
    for (int i = 0; i < 4; ++i) {
      const int chunk = i * 4 + wave;
      const int rr = chunk * 8 + srow;
      gload_lds16(Bt + (size_t)(n0 + rr) * K + (k0 + scol), &sB[chunk * 512]);
    }
    __syncthreads();
#pragma unroll
    for (int kk = 0; kk < 64; kk += 32) {
      const int kcol = kk + (lane >> 4) * 8;
      const int kswz = (lane & 7) * 8;
      short8 af[4], bfr[4];
#pragma unroll
      for (int m = 0; m < 4; ++m)
        af[m] = *(const short8*)&sA[(wr * 64 + m * 16 + (lane & 15)) * 64 + (kcol ^ kswz)];
#pragma unroll
      for (int n = 0; n < 4; ++n)
        bfr[n] = *(const short8*)&sB[(wc * 64 + n * 16 + (lane & 15)) * 64 + (kcol ^ kswz)];
#pragma unroll
      for (int m = 0; m < 4; ++m)
#pragma unroll
        for (int n = 0; n < 4; ++n)
          acc[m][n] = __builtin_amdgcn_mfma_f32_16x16x32_bf16(af[m], bfr[n], acc[m][n], 0, 0, 0);
    }
    __syncthreads();
  }

  const int cl = lane & 15, rg = lane >> 4;
  const float* bptr = (split == 0) ? bias : nullptr;
#pragma unroll
  for (int n = 0; n < 4; ++n) {
    const int col = n0 + wc * 64 + n * 16 + cl;
    const float bias_v = bptr ? bptr[col] : 0.0f;
#pragma unroll
    for (int m = 0; m < 4; ++m) {
      const int rbase = m0 + wr * 64 + m * 16 + rg * 4;
#pragma unroll
      for (int j2 = 0; j2 < 4; ++j2) {
        float v = acc[m][n][j2] + bias_v;
        if (RELU) v = fmaxf(v, 0.0f);
        const size_t idx = split * cStride + (size_t)(rbase + j2) * N + col;
        if (OUT_BF16) {
          // pack adjacent cols (cl, cl^1) into one ushort2 store
          unsigned int u = f2bf(v);
          unsigned int up = (unsigned int)__shfl_xor((int)u, 1);
          if ((cl & 1) == 0)
            *(unsigned int*)&((unsigned short*)Cout)[idx] = (u & 0xFFFFu) | (up << 16);
        } else {
          ((float*)Cout)[idx] = v;
        }
      }
    }
  }
}

// -------- LN (wave-per-row): h1 = LN(sum of 4 bf16 partials) -> bf16 --------
__global__ __launch_bounds__(256) void ln4_wave_kernel(
    const unsigned short* __restrict__ P, size_t pStr,
    const float* __restrict__ gg, const float* __restrict__ bb,
    unsigned short* __restrict__ Hb) {
  const int wave = threadIdx.x >> 6, lane = threadIdx.x & 63;
  const int row = blockIdx.x * 4 + wave;
  const size_t rbase = (size_t)row * 1024;
  float a[16];
#pragma unroll
  for (int sw = 0; sw < 2; ++sw) {
    const size_t idx = rbase + sw * 512 + lane * 8;
    ushort8 v0 = *(const ushort8*)(P + idx);
    ushort8 v1 = *(const ushort8*)(P + pStr + idx);
    ushort8 v2 = *(const ushort8*)(P + 2 * pStr + idx);
    ushort8 v3 = *(const ushort8*)(P + 3 * pStr + idx);
#pragma unroll
    for (int j = 0; j < 8; ++j)
      a[sw * 8 + j] = bf2f(v0[j]) + bf2f(v1[j]) + bf2f(v2[j]) + bf2f(v3[j]);
  }
  float s = 0.f, ss = 0.f;
#pragma unroll
  for (int j = 0; j < 16; ++j) { s += a[j]; ss += a[j] * a[j]; }
#pragma unroll
  for (int off = 32; off > 0; off >>= 1) {
    s += __shfl_down(s, off);
    ss += __shfl_down(ss, off);
  }
  s = __shfl(s, 0);
  ss = __shfl(ss, 0);
  const float mean = s * (1.0f / 1024.0f);
  const float rstd = rsqrtf(ss * (1.0f / 1024.0f) - mean * mean + 1e-5f);
#pragma unroll
  for (int sw = 0; sw < 2; ++sw) {
    const int cbase = sw * 512 + lane * 8;
    float4 g0 = *(const float4*)(gg + cbase);
    float4 g1 = *(const float4*)(gg + cbase + 4);
    float4 b0 = *(const float4*)(bb + cbase);
    float4 b1 = *(const float4*)(bb + cbase + 4);
    const float* gp0 = &g0.x; const float* gp1 = &g1.x;
    const float* bp0 = &b0.x; const float* bp1 = &b1.x;
    ushort8 o;
#pragma unroll
    for (int j = 0; j < 4; ++j) {
      o[j]     = f2bf((a[sw * 8 + j]     - mean) * rstd * gp0[j] + bp0[j]);
      o[4 + j] = f2bf((a[sw * 8 + 4 + j] - mean) * rstd * gp1[j] + bp1[j]);
    }
    *(ushort8*)(Hb + rbase + cbase) = o;
  }
}

// -------- LN (wave-per-row): out = LN(h1 + sum of 4 bf16 partials) -> fp32 --------
__global__ __launch_bounds__(256) void ln_fin_wave_kernel(
    const unsigned short* __restrict__ Res, const unsigned short* __restrict__ P,
    size_t pStr, const float* __restrict__ gg, const float* __restrict__ bb,
    float* __restrict__ out) {
  const int wave = threadIdx.x >> 6, lane = threadIdx.x & 63;
  const int row = blockIdx.x * 4 + wave;
  const size_t rbase = (size_t)row * 1024;
  float a[16];
#pragma unroll
  for (int sw = 0; sw < 2; ++sw) {
    const size_t idx = rbase + sw * 512 + lane * 8;
    ushort8 rv = *(const ushort8*)(Res + idx);
    ushort8 v0 = *(const ushort8*)(P + idx);
    ushort8 v1 = *(const ushort8*)(P + pStr + idx);
    ushort8 v2 = *(const ushort8*)(P + 2 * pStr + idx);
    ushort8 v3 = *(const ushort8*)(P + 3 * pStr + idx);
#pragma unroll
    for (int j = 0; j < 8; ++j)
      a[sw * 8 + j] = bf2f(rv[j]) + bf2f(v0[j]) + bf2f(v1[j]) + bf2f(v2[j]) + bf2f(v3[j]);
  }
  float s = 0.f, ss = 0.f;
#pragma unroll
  for (int j = 0; j < 16; ++j) { s += a[j]; ss += a[j] * a[j]; }
#pragma unroll
  for (int off = 32; off > 0; off >>= 1) {
    s += __shfl_down(s, off);
    ss += __shfl_down(ss, off);
  }
  s = __shfl(s, 0);
  ss = __shfl(ss, 0);
  const float mean = s * (1.0f / 1024.0f);
  const float rstd = rsqrtf(ss * (1.0f / 1024.0f) - mean * mean + 1e-5f);
#pragma unroll
  for (int sw = 0; sw < 2; ++sw) {
    const int cbase = sw * 512 + lane * 8;
    float4 g0 = *(const float4*)(gg + cbase);
    float4 g1 = *(const float4*)(gg + cbase + 4);
    float4 b0 = *(const float4*)(bb + cbase);
    float4 b1 = *(const float4*)(bb + cbase + 4);
    const float* gp0 = &g0.x; const float* gp1 = &g1.x;
    const float* bp0 = &b0.x; const float* bp1 = &b1.x;
    float4 o0, o1;
    float* op0 = &o0.x; float* op1 = &o1.x;
#pragma unroll
    for (int j = 0; j < 4; ++j) {
      op0[j] = (a[sw * 8 + j]     - mean) * rstd * gp0[j] + bp0[j];
      op1[j] = (a[sw * 8 + 4 + j] - mean) * rstd * gp1[j] + bp1[j];
    }
    *(float4*)(out + rbase + cbase) = o0;
    *(float4*)(out + rbase + cbase + 4) = o1;
  }
}

// ---------------------------------------------------------------------------
// Attention is algebraically dead: softmax over q sums to 1 per (b,h,k) column;
// summed over k -> s_bh == S == 2048 exactly. Folding the residual too:
//   h1  = LN( z @ (I + 2048*Wv@Wo) + (2048*bv@Wo + bo) )
//   out = LN( h1 + relu(h1@W1+b1)@W2 + b2 )
// q, k, mask, x, y, Wq, Wk are all unused.
// ---------------------------------------------------------------------------
extern "C" void kernel_launch(void* const* d_in, const int* in_sizes, int n_in,
                              void* d_out, int out_size, void* d_ws, size_t ws_size,
                              hipStream_t stream) {
  const float* z  = (const float*)d_in[2];
  const float* Wv = (const float*)d_in[8];
  const float* bv = (const float*)d_in[9];
  const float* Wo = (const float*)d_in[10];
  const float* bo = (const float*)d_in[11];
  const float* W1 = (const float*)d_in[12];
  const float* b1 = (const float*)d_in[13];
  const float* W2 = (const float*)d_in[14];
  const float* b2 = (const float*)d_in[15];
  const float* lng = (const float*)d_in[16];
  const float* lnb = (const float*)d_in[17];
  float* out = (float*)d_out;

  char* ws = (char*)d_ws;
  // layout (MB offsets), peak 112MB, lifetimes checked (r13):
  unsigned short* a1   = (unsigned short*)(ws + 0 * MB);
  unsigned short* attP = (unsigned short*)(ws + 32 * MB);
  unsigned short* ffP  = (unsigned short*)(ws + 32 * MB);
  unsigned short* W2T  = (unsigned short*)(ws + 64 * MB);
  unsigned short* wcpB = (unsigned short*)(ws + 72 * MB);
  unsigned short* WoT  = (unsigned short*)(ws + 88 * MB);
  unsigned short* WvBf = (unsigned short*)(ws + 90 * MB);
  unsigned short* WcT  = (unsigned short*)(ws + 92 * MB);
  float*          bc   = (float*)(ws + 94 * MB);
  float*          bprt = (float*)(ws + 94 * MB + 65536);
  unsigned short* h1bf = (unsigned short*)(ws + 96 * MB);
  unsigned short* W1T  = (unsigned short*)(ws + 104 * MB);

  const size_t pStr = (size_t)kM * kD;     // elements per activation partial
  const size_t wStr = (size_t)kD * kD;     // elements per Wc partial

  // 1) merged weight prep (WoT, W1T, W2T, WvBf, bprt)
  prep_kernel<<<dim3(3456), dim3(256), 0, stream>>>(
      Wo, Wv, W1, W2, bv, WoT, WvBf, W1T, W2T, bprt);

  // 2) Wc partials = (2048*Wv@Wo)^T : split-K x4 (grid 256, K=4 steps)
  gemm_bt<1, 0, 0><<<dim3(256), dim3(256), 0, stream>>>(
      WoT, WvBf, nullptr, wcpB, kD, kD, kD, kD / 128, 64, 256, wStr, 8, 4);

  // 3) WcT = sum of partials + I (bf16); blocks 0-3 also finish bc
  combine_wc4_fin_kernel<<<dim3(1024), dim3(256), 0, stream>>>(
      wcpB, WcT, bprt, bo, bc);

  // 4) attP = z @ WcT^T + bc : split-K x4 (grid 1024), A staged fp32->bf16,
  //    chunk 8x8 (L2-resident)
  gemm_bt<1, 0, 1><<<dim3(1024), dim3(256), 0, stream>>>(
      z, WcT, bc, attP, kM, kD, kD, kD / 128, 256, 256, pStr, 8, 8);

  // 5) h1 = LN(attP0..3) -> bf16 (wave-per-row)
  ln4_wave_kernel<<<dim3(kM / 4), dim3(256), 0, stream>>>(
      attP, pStr, lng, lnb, h1bf);

  // 6) FF1: a1 = relu(h1 @ W1 + b1) : grid 1024, chunk 8x8 (WS 4MB = L2)
  gemm_bt<1, 1, 0><<<dim3(1024), dim3(256), 0, stream>>>(
      h1bf, W1T, b1, a1, kM, kFF, kD, kFF / 128, 1024, kD, 0, 8, 8);

  // 7) FF2: ffP = a1 @ W2 + b2 : split-K x4 (grid 1024), chunk 8x8
  gemm_bt<1, 0, 0><<<dim3(1024), dim3(256), 0, stream>>>(
      a1, W2T, b2, ffP, kM, kD, kFF, kD / 128, 256, kFF / 4, pStr, 8, 8);

  // 8) out = LN(h1 + ffP0..3) (wave-per-row)
  ln_fin_wave_kernel<<<dim3(kM / 4), dim3(256), 0, stream>>>(
      h1bf, ffP, pStr, lng, lnb, out);
}

// Round 16
// 145.598 us; speedup vs baseline: 1.0857x; 1.0832x over previous
//
#include <hip/hip_runtime.h>

// Problem constants (from reference)
static constexpr int kB = 2, kS = 2048, kD = 1024, kFF = 4096;
static constexpr int kM = kB * kS;  // 4096 token rows
static constexpr size_t MB = 1u << 20;

typedef __attribute__((ext_vector_type(8))) short short8;
typedef __attribute__((ext_vector_type(8))) unsigned short ushort8;
typedef __attribute__((ext_vector_type(4))) float f32x4;

__device__ __forceinline__ unsigned short f2bf(float f) {
  union { float f; unsigned int u; } c; c.f = f;
  unsigned int u = c.u;
  unsigned int r = u + 0x7FFFu + ((u >> 16) & 1u);  // RNE
  return (unsigned short)(r >> 16);
}

__device__ __forceinline__ float bf2f(unsigned short b) {
  union { unsigned int u; float f; } c;
  c.u = ((unsigned int)b) << 16;
  return c.f;
}

__device__ __forceinline__ void gload_lds16(const void* g, void* l) {
  __builtin_amdgcn_global_load_lds(
      (const __attribute__((address_space(1))) void*)g,
      (__attribute__((address_space(3))) void*)l, 16, 0, 0);
}

// ------ cast+transpose 64x64 tile helper (used inside merged prep kernel) ------
__device__ __forceinline__ void do_ct64(
    const float* __restrict__ W, unsigned short* __restrict__ Wt,
    int K, int N, float scale, int ntN, int b, float (*tile)[65]) {
  const int nb = (b % ntN) * 64, kb = (b / ntN) * 64;
  const int tx = threadIdx.x & 15, ty = threadIdx.x >> 4;
#pragma unroll
  for (int p = 0; p < 4; ++p) {
    const int r = ty + 16 * p;
    float4 v = *(const float4*)(W + (size_t)(kb + r) * N + nb + tx * 4);
    tile[r][tx * 4 + 0] = v.x;
    tile[r][tx * 4 + 1] = v.y;
    tile[r][tx * 4 + 2] = v.z;
    tile[r][tx * 4 + 3] = v.w;
  }
  __syncthreads();
#pragma unroll
  for (int p = 0; p < 4; ++p) {
    const int n = ty + 16 * p;
    ushort4 o;
    o.x = f2bf(tile[tx * 4 + 0][n] * scale);
    o.y = f2bf(tile[tx * 4 + 1][n] * scale);
    o.z = f2bf(tile[tx * 4 + 2][n] * scale);
    o.w = f2bf(tile[tx * 4 + 3][n] * scale);
    *(ushort4*)(Wt + (size_t)(nb + n) * K + kb + tx * 4) = o;
  }
}

// ---- merged weight prep: Wo^T(x2048), W1^T, W2^T, cast(Wv), bias-GEMV part ----
__global__ __launch_bounds__(256) void prep_kernel(
    const float* __restrict__ Wo, const float* __restrict__ Wv,
    const float* __restrict__ W1, const float* __restrict__ W2,
    const float* __restrict__ bv,
    unsigned short* __restrict__ WoT, unsigned short* __restrict__ WvBf,
    unsigned short* __restrict__ W1T, unsigned short* __restrict__ W2T,
    float* __restrict__ bprt) {
  __shared__ float tile[64][65];
  const int b = blockIdx.x;
  if (b < 256) {
    do_ct64(Wo, WoT, kD, kD, (float)kS, 16, b, tile);
  } else if (b < 1280) {
    do_ct64(W1, W1T, kD, kFF, 1.0f, 64, b - 256, tile);
  } else if (b < 2304) {
    do_ct64(W2, W2T, kFF, kD, 1.0f, 16, b - 1280, tile);
  } else if (b < 3328) {
    const int i = ((b - 2304) * 256 + threadIdx.x) * 4;
    float4 v = *(const float4*)(Wv + i);
    ushort4 o;
    o.x = f2bf(v.x); o.y = f2bf(v.y); o.z = f2bf(v.z); o.w = f2bf(v.w);
    *(ushort4*)(WvBf + i) = o;
  } else {
    const int bb = b - 3328, t = threadIdx.x;
    const int c = t * 4;
    float4 acc = {0.f, 0.f, 0.f, 0.f};
#pragma unroll
    for (int r = 0; r < 8; ++r) {
      const int f = bb * 8 + r;
      const float s = bv[f];
      float4 w = *(const float4*)(Wo + (size_t)f * 1024 + c);
      acc.x = fmaf(s, w.x, acc.x);
      acc.y = fmaf(s, w.y, acc.y);
      acc.z = fmaf(s, w.z, acc.z);
      acc.w = fmaf(s, w.w, acc.w);
    }
    *(float4*)(bprt + (size_t)bb * 1024 + c) = acc;
  }
}

// -------- combine 4 bf16 Wc partials + I -> WcT bf16; blocks 0-3 also finish bc ----
__global__ __launch_bounds__(256) void combine_wc4_fin_kernel(
    const unsigned short* __restrict__ P, unsigned short* __restrict__ Wt,
    const float* __restrict__ bprt, const float* __restrict__ bo,
    float* __restrict__ bc) {
  const int i = (blockIdx.x * 256 + threadIdx.x) * 4;  // grid 1024
  const int MN = 1024 * 1024;
  ushort4 s0 = *(const ushort4*)(P + i);
  ushort4 s1 = *(const ushort4*)(P + MN + i);
  ushort4 s2 = *(const ushort4*)(P + 2 * MN + i);
  ushort4 s3 = *(const ushort4*)(P + 3 * MN + i);
  const int row = i >> 10, col = i & 1023;
  float v0 = bf2f(s0.x) + bf2f(s1.x) + bf2f(s2.x) + bf2f(s3.x) + (row == col + 0 ? 1.0f : 0.0f);
  float v1 = bf2f(s0.y) + bf2f(s1.y) + bf2f(s2.y) + bf2f(s3.y) + (row == col + 1 ? 1.0f : 0.0f);
  float v2 = bf2f(s0.z) + bf2f(s1.z) + bf2f(s2.z) + bf2f(s3.z) + (row == col + 2 ? 1.0f : 0.0f);
  float v3 = bf2f(s0.w) + bf2f(s1.w) + bf2f(s2.w) + bf2f(s3.w) + (row == col + 3 ? 1.0f : 0.0f);
  ushort4 o; o.x = f2bf(v0); o.y = f2bf(v1); o.z = f2bf(v2); o.w = f2bf(v3);
  *(ushort4*)(Wt + i) = o;
  if (blockIdx.x < 4) {
    const int n = blockIdx.x * 256 + threadIdx.x;
    float acc = 0.0f;
#pragma unroll 8
    for (int bb = 0; bb < 128; ++bb) acc += bprt[(size_t)bb * 1024 + n];
    bc[n] = 2048.0f * acc + bo[n];
  }
}

// ---------------- GEMM: C[M,N] = A[M,K] @ Bt[N,K]^T (+bias, relu, split-K) ----
// 128x128 tile, BK=64, 4 waves (2x2). Single 32KB LDS buffer (m97 structure;
// 4 blocks/CU TLP -- the hard cap: 60 VGPR + 64 acc-AGPR ~ 124 regs/wave;
// r14 proved bigger wave-tiles lose to occupancy, r15 proved store-packing
// loses to epilogue serialization -- plain stores, plain tiles).
// T2 XOR-swizzle (0 conflicts measured). XCD super-chunk mapping (r10).
// A_F32: stage A fp32->reg->cvt->ds_write (fuses the z cast).
template <int OUT_BF16, int RELU, int A_F32>
__global__ __launch_bounds__(256, 4) void gemm_bt(
    const void* __restrict__ A, const unsigned short* __restrict__ Bt,
    const float* __restrict__ bias, void* __restrict__ Cout,
    int M, int N, int K, int nXtiles, int nTilesPerSplit, int kSplitLen,
    size_t cStride, int cr, int cc) {
  __shared__ __align__(16) unsigned short sA[128 * 64];
  __shared__ __align__(16) unsigned short sB[128 * 64];
  const unsigned short* Ab = (const unsigned short*)A;
  const float* Af = (const float*)A;
  const int tid = threadIdx.x;
  const int wave = tid >> 6, lane = tid & 63;
  const int wr = wave >> 1, wc = wave & 1;

  // super-chunk XCD decomposition (bijective; (nwg/8) % (cr*cc) == 0)
  const int x = blockIdx.x & 7, j = blockIdx.x >> 3;
  const int bpc = cr * cc;
  const int chunkIdx = x + 8 * (j / bpc);
  const int w = j % bpc;
  const int chunksPerSplit = nTilesPerSplit / bpc;
  const int split = chunkIdx / chunksPerSplit;
  const int cL = chunkIdx % chunksPerSplit;
  const int cpr = nXtiles / cc;
  const int m0 = ((cL / cpr) * cr + w / cc) * 128;
  const int n0 = ((cL % cpr) * cc + w % cc) * 128;
  const int kBeg = split * kSplitLen, kEnd = kBeg + kSplitLen;

  const int srow = lane >> 3;
  const int scol = ((lane & 7) ^ srow) * 8;  // pre-swizzled global col (elements)

  f32x4 acc[4][4] = {};

  for (int k0 = kBeg; k0 < kEnd; k0 += 64) {
    if constexpr (A_F32) {
      float4 pa[4][2];
#pragma unroll
      for (int i = 0; i < 4; ++i) {
        const int chunk = i * 4 + wave;
        const int rr = chunk * 8 + srow;
        const float* az = Af + (size_t)(m0 + rr) * K + (k0 + scol);
        pa[i][0] = *(const float4*)az;
        pa[i][1] = *(const float4*)(az + 4);
      }
#pragma unroll
      for (int i = 0; i < 4; ++i) {
        const int chunk = i * 4 + wave;
        short8 cv;
        cv[0] = (short)f2bf(pa[i][0].x); cv[1] = (short)f2bf(pa[i][0].y);
        cv[2] = (short)f2bf(pa[i][0].z); cv[3] = (short)f2bf(pa[i][0].w);
        cv[4] = (short)f2bf(pa[i][1].x); cv[5] = (short)f2bf(pa[i][1].y);
        cv[6] = (short)f2bf(pa[i][1].z); cv[7] = (short)f2bf(pa[i][1].w);
        *(short8*)&sA[chunk * 512 + lane * 8] = cv;
      }
    } else {
#pragma unroll
      for (int i = 0; i < 4; ++i) {
        const int chunk = i * 4 + wave;
        const int rr = chunk * 8 + srow;
        gload_lds16(Ab + (size_t)(m0 + rr) * K + (k0 + scol), &sA[chunk * 512]);
      }
    }
#pragma unroll
    for (int i = 0; i < 4; ++i) {
      const int chunk = i * 4 + wave;
      const int rr = chunk * 8 + srow;
      gload_lds16(Bt + (size_t)(n0 + rr) * K + (k0 + scol), &sB[chunk * 512]);
    }
    __syncthreads();
#pragma unroll
    for (int kk = 0; kk < 64; kk += 32) {
      const int kcol = kk + (lane >> 4) * 8;
      const int kswz = (lane & 7) * 8;
      short8 af[4], bfr[4];
#pragma unroll
      for (int m = 0; m < 4; ++m)
        af[m] = *(const short8*)&sA[(wr * 64 + m * 16 + (lane & 15)) * 64 + (kcol ^ kswz)];
#pragma unroll
      for (int n = 0; n < 4; ++n)
        bfr[n] = *(const short8*)&sB[(wc * 64 + n * 16 + (lane & 15)) * 64 + (kcol ^ kswz)];
#pragma unroll
      for (int m = 0; m < 4; ++m)
#pragma unroll
        for (int n = 0; n < 4; ++n)
          acc[m][n] = __builtin_amdgcn_mfma_f32_16x16x32_bf16(af[m], bfr[n], acc[m][n], 0, 0, 0);
    }
    __syncthreads();
  }

  const int cl = lane & 15, rg = lane >> 4;
  const float* bptr = (split == 0) ? bias : nullptr;
#pragma unroll
  for (int n = 0; n < 4; ++n) {
    const int col = n0 + wc * 64 + n * 16 + cl;
    const float bias_v = bptr ? bptr[col] : 0.0f;
#pragma unroll
    for (int m = 0; m < 4; ++m) {
      const int rbase = m0 + wr * 64 + m * 16 + rg * 4;
#pragma unroll
      for (int j2 = 0; j2 < 4; ++j2) {
        float v = acc[m][n][j2] + bias_v;
        if (RELU) v = fmaxf(v, 0.0f);
        const size_t idx = split * cStride + (size_t)(rbase + j2) * N + col;
        if (OUT_BF16)
          ((unsigned short*)Cout)[idx] = f2bf(v);
        else
          ((float*)Cout)[idx] = v;
      }
    }
  }
}

// -------- LN (wave-per-row): h1 = LN(sum of 4 bf16 partials) -> bf16 --------
__global__ __launch_bounds__(256) void ln4_wave_kernel(
    const unsigned short* __restrict__ P, size_t pStr,
    const float* __restrict__ gg, const float* __restrict__ bb,
    unsigned short* __restrict__ Hb) {
  const int wave = threadIdx.x >> 6, lane = threadIdx.x & 63;
  const int row = blockIdx.x * 4 + wave;
  const size_t rbase = (size_t)row * 1024;
  float a[16];
#pragma unroll
  for (int sw = 0; sw < 2; ++sw) {
    const size_t idx = rbase + sw * 512 + lane * 8;
    ushort8 v0 = *(const ushort8*)(P + idx);
    ushort8 v1 = *(const ushort8*)(P + pStr + idx);
    ushort8 v2 = *(const ushort8*)(P + 2 * pStr + idx);
    ushort8 v3 = *(const ushort8*)(P + 3 * pStr + idx);
#pragma unroll
    for (int j = 0; j < 8; ++j)
      a[sw * 8 + j] = bf2f(v0[j]) + bf2f(v1[j]) + bf2f(v2[j]) + bf2f(v3[j]);
  }
  float s = 0.f, ss = 0.f;
#pragma unroll
  for (int j = 0; j < 16; ++j) { s += a[j]; ss += a[j] * a[j]; }
#pragma unroll
  for (int off = 32; off > 0; off >>= 1) {
    s += __shfl_down(s, off);
    ss += __shfl_down(ss, off);
  }
  s = __shfl(s, 0);
  ss = __shfl(ss, 0);
  const float mean = s * (1.0f / 1024.0f);
  const float rstd = rsqrtf(ss * (1.0f / 1024.0f) - mean * mean + 1e-5f);
#pragma unroll
  for (int sw = 0; sw < 2; ++sw) {
    const int cbase = sw * 512 + lane * 8;
    float4 g0 = *(const float4*)(gg + cbase);
    float4 g1 = *(const float4*)(gg + cbase + 4);
    float4 b0 = *(const float4*)(bb + cbase);
    float4 b1 = *(const float4*)(bb + cbase + 4);
    const float* gp0 = &g0.x; const float* gp1 = &g1.x;
    const float* bp0 = &b0.x; const float* bp1 = &b1.x;
    ushort8 o;
#pragma unroll
    for (int j = 0; j < 4; ++j) {
      o[j]     = f2bf((a[sw * 8 + j]     - mean) * rstd * gp0[j] + bp0[j]);
      o[4 + j] = f2bf((a[sw * 8 + 4 + j] - mean) * rstd * gp1[j] + bp1[j]);
    }
    *(ushort8*)(Hb + rbase + cbase) = o;
  }
}

// -------- LN (wave-per-row): out = LN(h1 + sum of 4 bf16 partials) -> fp32 --------
__global__ __launch_bounds__(256) void ln_fin_wave_kernel(
    const unsigned short* __restrict__ Res, const unsigned short* __restrict__ P,
    size_t pStr, const float* __restrict__ gg, const float* __restrict__ bb,
    float* __restrict__ out) {
  const int wave = threadIdx.x >> 6, lane = threadIdx.x & 63;
  const int row = blockIdx.x * 4 + wave;
  const size_t rbase = (size_t)row * 1024;
  float a[16];
#pragma unroll
  for (int sw = 0; sw < 2; ++sw) {
    const size_t idx = rbase + sw * 512 + lane * 8;
    ushort8 rv = *(const ushort8*)(Res + idx);
    ushort8 v0 = *(const ushort8*)(P + idx);
    ushort8 v1 = *(const ushort8*)(P + pStr + idx);
    ushort8 v2 = *(const ushort8*)(P + 2 * pStr + idx);
    ushort8 v3 = *(const ushort8*)(P + 3 * pStr + idx);
#pragma unroll
    for (int j = 0; j < 8; ++j)
      a[sw * 8 + j] = bf2f(rv[j]) + bf2f(v0[j]) + bf2f(v1[j]) + bf2f(v2[j]) + bf2f(v3[j]);
  }
  float s = 0.f, ss = 0.f;
#pragma unroll
  for (int j = 0; j < 16; ++j) { s += a[j]; ss += a[j] * a[j]; }
#pragma unroll
  for (int off = 32; off > 0; off >>= 1) {
    s += __shfl_down(s, off);
    ss += __shfl_down(ss, off);
  }
  s = __shfl(s, 0);
  ss = __shfl(ss, 0);
  const float mean = s * (1.0f / 1024.0f);
  const float rstd = rsqrtf(ss * (1.0f / 1024.0f) - mean * mean + 1e-5f);
#pragma unroll
  for (int sw = 0; sw < 2; ++sw) {
    const int cbase = sw * 512 + lane * 8;
    float4 g0 = *(const float4*)(gg + cbase);
    float4 g1 = *(const float4*)(gg + cbase + 4);
    float4 b0 = *(const float4*)(bb + cbase);
    float4 b1 = *(const float4*)(bb + cbase + 4);
    const float* gp0 = &g0.x; const float* gp1 = &g1.x;
    const float* bp0 = &b0.x; const float* bp1 = &b1.x;
    float4 o0, o1;
    float* op0 = &o0.x; float* op1 = &o1.x;
#pragma unroll
    for (int j = 0; j < 4; ++j) {
      op0[j] = (a[sw * 8 + j]     - mean) * rstd * gp0[j] + bp0[j];
      op1[j] = (a[sw * 8 + 4 + j] - mean) * rstd * gp1[j] + bp1[j];
    }
    *(float4*)(out + rbase + cbase) = o0;
    *(float4*)(out + rbase + cbase + 4) = o1;
  }
}

// ---------------------------------------------------------------------------
// Attention is algebraically dead: softmax over q sums to 1 per (b,h,k) column;
// summed over k -> s_bh == S == 2048 exactly. Folding the residual too:
//   h1  = LN( z @ (I + 2048*Wv@Wo) + (2048*bv@Wo + bo) )
//   out = LN( h1 + relu(h1@W1+b1)@W2 + b2 )
// q, k, mask, x, y, Wq, Wk are all unused.
// ---------------------------------------------------------------------------
extern "C" void kernel_launch(void* const* d_in, const int* in_sizes, int n_in,
                              void* d_out, int out_size, void* d_ws, size_t ws_size,
                              hipStream_t stream) {
  const float* z  = (const float*)d_in[2];
  const float* Wv = (const float*)d_in[8];
  const float* bv = (const float*)d_in[9];
  const float* Wo = (const float*)d_in[10];
  const float* bo = (const float*)d_in[11];
  const float* W1 = (const float*)d_in[12];
  const float* b1 = (const float*)d_in[13];
  const float* W2 = (const float*)d_in[14];
  const float* b2 = (const float*)d_in[15];
  const float* lng = (const float*)d_in[16];
  const float* lnb = (const float*)d_in[17];
  float* out = (float*)d_out;

  char* ws = (char*)d_ws;
  // layout (MB offsets), peak 112MB, lifetimes checked (r13):
  unsigned short* a1   = (unsigned short*)(ws + 0 * MB);
  unsigned short* attP = (unsigned short*)(ws + 32 * MB);
  unsigned short* ffP  = (unsigned short*)(ws + 32 * MB);
  unsigned short* W2T  = (unsigned short*)(ws + 64 * MB);
  unsigned short* wcpB = (unsigned short*)(ws + 72 * MB);
  unsigned short* WoT  = (unsigned short*)(ws + 88 * MB);
  unsigned short* WvBf = (unsigned short*)(ws + 90 * MB);
  unsigned short* WcT  = (unsigned short*)(ws + 92 * MB);
  float*          bc   = (float*)(ws + 94 * MB);
  float*          bprt = (float*)(ws + 94 * MB + 65536);
  unsigned short* h1bf = (unsigned short*)(ws + 96 * MB);
  unsigned short* W1T  = (unsigned short*)(ws + 104 * MB);

  const size_t pStr = (size_t)kM * kD;     // elements per activation partial
  const size_t wStr = (size_t)kD * kD;     // elements per Wc partial

  // 1) merged weight prep (WoT, W1T, W2T, WvBf, bprt)
  prep_kernel<<<dim3(3456), dim3(256), 0, stream>>>(
      Wo, Wv, W1, W2, bv, WoT, WvBf, W1T, W2T, bprt);

  // 2) Wc partials = (2048*Wv@Wo)^T : split-K x4 (grid 256, K=4 steps)
  gemm_bt<1, 0, 0><<<dim3(256), dim3(256), 0, stream>>>(
      WoT, WvBf, nullptr, wcpB, kD, kD, kD, kD / 128, 64, 256, wStr, 8, 4);

  // 3) WcT = sum of partials + I (bf16); blocks 0-3 also finish bc
  combine_wc4_fin_kernel<<<dim3(1024), dim3(256), 0, stream>>>(
      wcpB, WcT, bprt, bo, bc);

  // 4) attP = z @ WcT^T + bc : split-K x4 (grid 1024), A staged fp32->bf16
  gemm_bt<1, 0, 1><<<dim3(1024), dim3(256), 0, stream>>>(
      z, WcT, bc, attP, kM, kD, kD, kD / 128, 256, 256, pStr, 8, 8);

  // 5) h1 = LN(attP0..3) -> bf16 (wave-per-row)
  ln4_wave_kernel<<<dim3(kM / 4), dim3(256), 0, stream>>>(
      attP, pStr, lng, lnb, h1bf);

  // 6) FF1: a1 = relu(h1 @ W1 + b1) : grid 1024, chunk 16x8/XCD
  gemm_bt<1, 1, 0><<<dim3(1024), dim3(256), 0, stream>>>(
      h1bf, W1T, b1, a1, kM, kFF, kD, kFF / 128, 1024, kD, 0, 16, 8);

  // 7) FF2: ffP = a1 @ W2 + b2 : split-K x4 (grid 1024), chunk 16x8/XCD
  gemm_bt<1, 0, 0><<<dim3(1024), dim3(256), 0, stream>>>(
      a1, W2T, b2, ffP, kM, kD, kFF, kD / 128, 256, kFF / 4, pStr, 16, 8);

  // 8) out = LN(h1 + ffP0..3) (wave-per-row)
  ln_fin_wave_kernel<<<dim3(kM / 4), dim3(256), 0, stream>>>(
      h1bf, ffP, pStr, lng, lnb, out);
}